// Round 5
// baseline (135.305 us; speedup 1.0000x reference)
//
#include <hip/hip_runtime.h>

// CRF-RNN mean-field. Separable theta=3 convs + LOW-RANK theta=160 filter.
// Grid 24(z) x 24(y) x 16(x), N=9216, C=2, 5 iterations.
//
// Kb = S160 * E_i E_j * exp(I3_i I3_j); intensity Taylor NT=5 (err 1.4e-7):
//   fields f_{2t+c} = P_t * q_c,  P_t = I3^t * E.
// S160 over a z-slice: exp(-u s), u=1/51200, s = ||pi-pj||^2_2D <= 754
//   => poly order 2: 1 - u s + u^2 s^2/2 (rel err <= (us)^3/6 ~ 5e-7)
//   => slice filter = 9 moments/field {m0,mx,my,mxx,mxy,myy,mRx,mRy,mRR}
//      with point coeffs CF[9]; z-direction exact via g160z moment blending.
// Spatial theta=3 (2 fields) stays as real separable convs (xy in LDS,
// z across slices via tmpS).  Coords centered (xc=x-7.5, yc=y-11.5) for
// conditioning; moments are translation-invariant w.r.t. the filter.

#define DD 24
#define HH 24
#define WW 16
#define SLICE 384
#define NPTS 9216
#define NT 5
#define NF 10           // bilateral fields per iteration
#define MSTRIDE 96      // per-slice float stride of tmpM (90 used)
#define NSTRIDE 48      // per-slice float stride of tmpMN (45 used)
#define LOG2E 1.4426950408889634f
#define K3L   (LOG2E / 18.0f)
#define K160L (LOG2E / 51200.0f)
#define UU    (1.0f / 51200.0f)

static __device__ __forceinline__ int iabs(int a) { return a < 0 ? -a : a; }

static __device__ __forceinline__ float rowred16(float v) {
    v += __shfl_xor(v, 1, 16);
    v += __shfl_xor(v, 2, 16);
    v += __shfl_xor(v, 4, 16);
    v += __shfl_xor(v, 8, 16);
    return v;
}

// Per-slice 2D moments of NFF fields -> gdst[F*9+m]. Uniform call (syncs).
template <int NFF>
static __device__ void slice_moments(const float* f, const float* xpw,
                                     int y, int x, int t,
                                     float (*rowsum)[52], float* gdst) {
    for (int F = 0; F < NFF; ++F) {
#pragma unroll
        for (int a = 0; a < 5; ++a) {
            float r = rowred16(f[F] * xpw[a]);
            if (x == 0) rowsum[y][F * 5 + a] = r;
        }
    }
    __syncthreads();
    if (t < NFF) {
        float acc[9];
#pragma unroll
        for (int k = 0; k < 9; ++k) acc[k] = 0.f;
        for (int yy = 0; yy < HH; ++yy) {
            float yc = (float)yy - 11.5f;
            float yc2 = yc * yc, yc3 = yc2 * yc, yc4 = yc2 * yc2;
            const float* S = rowsum[yy] + t * 5;
            float S0 = S[0], S1 = S[1], S2 = S[2], S3 = S[3], S4 = S[4];
            acc[0] += S0;
            acc[1] += S1;
            acc[2] += yc * S0;
            acc[3] += S2;
            acc[4] += yc * S1;
            acc[5] += yc2 * S0;
            acc[6] += S3 + yc2 * S1;
            acc[7] += yc * S2 + yc3 * S0;
            acc[8] += S4 + 2.f * yc2 * S2 + yc4 * S0;
        }
#pragma unroll
        for (int k = 0; k < 9; ++k) gdst[t * 9 + k] = acc[k];
    }
    __syncthreads();   // rowsum reusable
}

// theta=3 separable xy conv of one float2 field. Uniform call (syncs).
static __device__ void xyconv2(float2 q, int y, int x, const float* g3s,
                               float2 (*cA)[17], float2 (*cB)[17], float2* ov) {
    cA[y][x] = q;
    __syncthreads();
    float a0 = 0.f, a1 = 0.f;
#pragma unroll
    for (int xp = 0; xp < WW; ++xp) {
        float w = g3s[iabs(x - xp)];
        float2 v = cA[y][xp];
        a0 = fmaf(w, v.x, a0);
        a1 = fmaf(w, v.y, a1);
    }
    cB[y][x] = make_float2(a0, a1);
    __syncthreads();
    float b0 = 0.f, b1 = 0.f;
#pragma unroll
    for (int yp = 0; yp < HH; ++yp) {
        float w = g3s[iabs(y - yp)];
        float2 v = cB[yp][x];
        b0 = fmaf(w, v.x, b0);
        b1 = fmaf(w, v.y, b1);
    }
    *ov = make_float2(b0, b1);
    __syncthreads();   // cA/cB reusable
}

// ---- precompute: tmpS/tmpM from q=u, tmpMN from P_t --------------------
__global__ __launch_bounds__(SLICE)
void crf_pre(const float2* __restrict__ u2, const float* __restrict__ rgb,
             float2* __restrict__ tmpS, float* __restrict__ tmpM,
             float* __restrict__ tmpMN) {
    __shared__ float g3s[32];
    __shared__ float2 cA[HH][17];
    __shared__ float2 cB[HH][17];
    __shared__ float rowsum[HH][52];

    const int z = blockIdx.x, t = threadIdx.x;
    const int y = t >> 4, x = t & 15;
    const int i = z * SLICE + t;

    if (t < DD) g3s[t] = exp2f(-(float)(t * t) * K3L);
    __syncthreads();

    const float I3 = rgb[i] * (1.f / 3.f);
    const float E = exp2f(-0.5f * LOG2E * I3 * I3);
    float Pt[NT];
    Pt[0] = E;
#pragma unroll
    for (int k = 1; k < NT; ++k) Pt[k] = Pt[k - 1] * I3;
    const float2 qq = u2[i];

    float2 sxy;
    xyconv2(qq, y, x, g3s, cA, cB, &sxy);
    tmpS[i] = sxy;

    const float xc = (float)x - 7.5f;
    float xpw[5] = {1.f, xc, xc * xc, xc * xc * xc, xc * xc * xc * xc};

    float f[NF];
#pragma unroll
    for (int k = 0; k < NT; ++k) { f[2 * k] = Pt[k] * qq.x; f[2 * k + 1] = Pt[k] * qq.y; }
    slice_moments<NF>(f, xpw, y, x, t, rowsum, tmpM + z * MSTRIDE);

    float fN[NT];
#pragma unroll
    for (int k = 0; k < NT; ++k) fN[k] = Pt[k];
    slice_moments<NT>(fN, xpw, y, x, t, rowsum, tmpMN + z * NSTRIDE);
}

// ---- one mean-field iteration ------------------------------------------
__global__ __launch_bounds__(SLICE)
void crf_iter(const float2* __restrict__ tmpS_src, const float* __restrict__ tmpM_src,
              const float* __restrict__ tmpMN,
              float2* __restrict__ tmpS_dst, float* __restrict__ tmpM_dst,
              const float* __restrict__ rgb, const float2* __restrict__ u2,
              const float* __restrict__ sw, const float* __restrict__ bw,
              const float* __restrict__ compat,
              float2* __restrict__ out, int it) {
    __shared__ float g3s[32];
    __shared__ float g160zs[32];
    __shared__ float2 cA[HH][17];
    __shared__ float2 cB[HH][17];
    __shared__ float rowsum[HH][52];
    __shared__ float MbS[90];
    __shared__ float MbNS[45];

    const int z = blockIdx.x, t = threadIdx.x;
    const int y = t >> 4, x = t & 15;
    const int i = z * SLICE + t;

    if (t < DD) {
        g3s[t] = exp2f(-(float)(t * t) * K3L);
        g160zs[t] = exp2f(-(float)(t * t) * K160L);
    }
    __syncthreads();

    // spatial z-conv (theta=3) over tmpS
    float zs0 = 0.f, zs1 = 0.f;
    for (int zp = 0; zp < DD; ++zp) {
        float w = g3s[iabs(z - zp)];
        float2 v = tmpS_src[zp * SLICE + t];
        zs0 = fmaf(w, v.x, zs0);
        zs1 = fmaf(w, v.y, zs1);
    }

    // moment z-blend (exact exp in z)
    if (t < 90) {
        float acc = 0.f;
        for (int zp = 0; zp < DD; ++zp)
            acc = fmaf(g160zs[iabs(z - zp)], tmpM_src[zp * MSTRIDE + t], acc);
        MbS[t] = acc;
    } else if (t >= 128 && t < 173) {
        int m = t - 128;
        float acc = 0.f;
        for (int zp = 0; zp < DD; ++zp)
            acc = fmaf(g160zs[iabs(z - zp)], tmpMN[zp * NSTRIDE + m], acc);
        MbNS[m] = acc;
    }
    __syncthreads();

    // per-point constants
    const float xc = (float)x - 7.5f, yc = (float)y - 11.5f;
    const float Ri = xc * xc + yc * yc;
    const float uq = UU * UU;
    const float omuR = 1.f - UU * Ri;
    float CF[9];
    CF[0] = 1.f - UU * Ri + 0.5f * uq * Ri * Ri;
    CF[1] = 2.f * UU * xc * omuR;
    CF[2] = 2.f * UU * yc * omuR;
    CF[3] = (-UU + uq * Ri) + 2.f * uq * xc * xc;
    CF[4] = 4.f * uq * xc * yc;
    CF[5] = (-UU + uq * Ri) + 2.f * uq * yc * yc;
    CF[6] = -2.f * uq * xc;
    CF[7] = -2.f * uq * yc;
    CF[8] = 0.5f * uq;

    const float I3 = rgb[i] * (1.f / 3.f);
    const float E = exp2f(-0.5f * LOG2E * I3 * I3);
    float Pt[NT];
    Pt[0] = E;
#pragma unroll
    for (int k = 1; k < NT; ++k) Pt[k] = Pt[k - 1] * I3;
    const float invf[NT] = {1.f, 1.f, 0.5f, 1.f / 6.f, 1.f / 24.f};

    float sxn = 0.f, syn = 0.f, szn = 0.f;
#pragma unroll
    for (int xp = 0; xp < WW; ++xp) sxn += g3s[iabs(x - xp)];
#pragma unroll
    for (int yp = 0; yp < HH; ++yp) syn += g3s[iabs(y - yp)];
#pragma unroll
    for (int zp = 0; zp < DD; ++zp) szn += g3s[iabs(z - zp)];
    const float inv_ns = 1.0f / (sxn * syn * szn);

    // bilateral reconstruction from blended moments
    float nb = 0.f, b0 = 0.f, b1 = 0.f;
#pragma unroll
    for (int k = 0; k < NT; ++k) {
        float w = Pt[k] * invf[k];
        float sN = 0.f, s0 = 0.f, s1 = 0.f;
        const float* MN = MbNS + k * 9;
        const float* M0 = MbS + (2 * k) * 9;
        const float* M1 = MbS + (2 * k + 1) * 9;
#pragma unroll
        for (int m = 0; m < 9; ++m) {
            sN = fmaf(CF[m], MN[m], sN);
            s0 = fmaf(CF[m], M0[m], s0);
            s1 = fmaf(CF[m], M1[m], s1);
        }
        nb = fmaf(w, sN, nb);
        b0 = fmaf(w, s0, b0);
        b1 = fmaf(w, s1, b1);
    }
    float inv_nb = 1.0f / nb;
    b0 *= inv_nb;
    b1 *= inv_nb;

    // mean-field update
    float s0 = zs0 * inv_ns;
    float s1 = zs1 * inv_ns;
    float m0 = s0 * sw[0] + b0 * bw[0];
    float m1 = s1 * sw[1] + b1 * bw[1];
    float p0 = fmaf(compat[0], m0, compat[1] * m1);
    float p1 = fmaf(compat[2], m0, compat[3] * m1);
    const float2 uu = u2[i];
    float q0 = uu.x - p0;
    float q1 = uu.y - p1;

    if (it == 4) {
        out[i] = make_float2(q0, q1);
        return;
    }

    // produce next iteration's tmpS / tmpM
    float2 sxy;
    xyconv2(make_float2(q0, q1), y, x, g3s, cA, cB, &sxy);
    tmpS_dst[i] = sxy;

    float xpw[5] = {1.f, xc, xc * xc, xc * xc * xc, xc * xc * xc * xc};
    float f[NF];
#pragma unroll
    for (int k = 0; k < NT; ++k) { f[2 * k] = Pt[k] * q0; f[2 * k + 1] = Pt[k] * q1; }
    slice_moments<NF>(f, xpw, y, x, t, rowsum, tmpM_dst + z * MSTRIDE);
}

extern "C" void kernel_launch(void* const* d_in, const int* in_sizes, int n_in,
                              void* d_out, int out_size, void* d_ws, size_t ws_size,
                              hipStream_t stream) {
    const float2* u2     = (const float2*)d_in[0];
    const float*  rgb    = (const float*)d_in[1];
    const float*  sw     = (const float*)d_in[2];
    const float*  bw     = (const float*)d_in[3];
    const float*  compat = (const float*)d_in[4];
    float2* out = (float2*)d_out;

    float* ws = (float*)d_ws;
    float2* tmpS_A = (float2*)ws;                         // NPTS float2
    float2* tmpS_B = (float2*)(ws + 2 * NPTS);            // NPTS float2
    float*  tmpM_A = ws + 4 * NPTS;                       // DD*MSTRIDE
    float*  tmpM_B = tmpM_A + DD * MSTRIDE;               // DD*MSTRIDE
    float*  tmpMN  = tmpM_B + DD * MSTRIDE;               // DD*NSTRIDE

    crf_pre<<<DD, SLICE, 0, stream>>>(u2, rgb, tmpS_A, tmpM_A, tmpMN);

    const float2* sS = tmpS_A; float2* dS = tmpS_B;
    const float*  sM = tmpM_A; float*  dM = tmpM_B;
    for (int it = 0; it < 5; ++it) {
        crf_iter<<<DD, SLICE, 0, stream>>>(sS, sM, tmpMN, dS, dM,
                                           rgb, u2, sw, bw, compat, out, it);
        const float2* nS = dS; dS = (float2*)sS; sS = nS;
        const float*  nM = dM; dM = (float*)sM; sM = nM;
    }
}

// Round 6
// 109.371 us; speedup vs baseline: 1.2371x; 1.2371x over previous
//
#include <hip/hip_runtime.h>

// CRF-RNN mean-field, separable filters, FIELD-PARALLEL kernels.
// Grid 24(z) x 24(y) x 16(x), N=9216, C=2, 5 iterations.
//
// Ks (theta=3) = Gz (x) Gy (x) Gx  -- exact separable 1-D convs.
// Kb = S160 * E_i E_j * exp(I3_i*I3_j), Taylor NT=5 (err ~1e-7).
// 12 iter fields: f0,f1 = q (theta=3); f(2+2t+c) = P_t*q_c (theta=160).
// 5 norm fields (planes 12..16): P_t (theta=160), filtered once.
//
// Lesson R2/R4/R5: every kernel boundary restarts with cold L2 (CP wb/inv
// gives cross-XCD correctness), so per-kernel cost ~ bytes-reread / CUs
// active. 24-block kernels concentrate 10.6 MB on 24 CUs (~9 us) and the
// 12-field LDS conv on 24 CUs (~2.4 us). Fix: one FIELD per block ->
// 288-block xy and z kernels, 36-block update kernel.

#define DD 24
#define HH 24
#define WW 16
#define SLICE 384
#define NPTS 9216
#define NT 5
#define NFI 12           // iteration fields
#define NFT 17           // + norm fields
#define LOG2E 1.4426950408889634f
#define K3L   (LOG2E / 18.0f)
#define K160L (LOG2E / 51200.0f)

static __device__ __forceinline__ int iabs(int a) { return a < 0 ? -a : a; }

// ---- xy separable conv, ONE field per block. grid (DD, nf) x SLICE ------
// f<2: v=q_c from qsrc. 2<=f<12: v=P_t*q_c. f>=12: v=P_{f-12} (norm).
__global__ __launch_bounds__(SLICE)
void k_xy(const float2* __restrict__ qsrc, const float* __restrict__ rgb,
          float* __restrict__ tmp) {
    __shared__ float gk[32];
    __shared__ float sA[HH][WW + 1];
    __shared__ float sB[HH][WW + 1];
    const int z = blockIdx.x, f = blockIdx.y, t = threadIdx.x;
    const int y = t >> 4, x = t & 15;
    const int i = z * SLICE + t;

    const float kk = (f < 2) ? K3L : K160L;
    if (t < DD) gk[t] = exp2f(-(float)(t * t) * kk);

    float v;
    if (f < 2) {
        float2 q = qsrc[i];
        v = (f == 0) ? q.x : q.y;
    } else {
        float I3 = rgb[i] * (1.f / 3.f);
        float E = exp2f(-0.5f * LOG2E * I3 * I3);
        int k = (f < NFI) ? ((f - 2) >> 1) : (f - NFI);
        float P = E;
        for (int s = 0; s < k; ++s) P *= I3;
        if (f < NFI) {
            float2 q = qsrc[i];
            v = P * (((f - 2) & 1) ? q.y : q.x);
        } else {
            v = P;
        }
    }
    sA[y][x] = v;
    __syncthreads();

    float a = 0.f;
#pragma unroll
    for (int xp = 0; xp < WW; ++xp) a = fmaf(gk[iabs(x - xp)], sA[y][xp], a);
    sB[y][x] = a;
    __syncthreads();

    float b = 0.f;
#pragma unroll
    for (int yp = 0; yp < HH; ++yp) b = fmaf(gk[iabs(y - yp)], sB[yp][x], b);
    tmp[f * NPTS + i] = b;
}

// ---- z conv, ONE field per block. grid (DD, nf) x SLICE -----------------
__global__ __launch_bounds__(SLICE)
void k_zconv(const float* __restrict__ tmp, float* __restrict__ zout) {
    __shared__ float gk[32];
    const int z = blockIdx.x, f = blockIdx.y, t = threadIdx.x;
    const float kk = (f < 2) ? K3L : K160L;
    if (t < DD) gk[t] = exp2f(-(float)(t * t) * kk);
    __syncthreads();

    float acc = 0.f;
    const float* p = tmp + f * NPTS + t;
#pragma unroll 4
    for (int zp = 0; zp < DD; ++zp)
        acc = fmaf(gk[iabs(z - zp)], p[zp * SLICE], acc);
    zout[f * NPTS + z * SLICE + t] = acc;
}

// ---- pointwise mean-field update. grid 36 x 256 -------------------------
__global__ __launch_bounds__(256)
void k_update(const float* __restrict__ zout, const float* __restrict__ rgb,
              const float2* __restrict__ u2,
              const float* __restrict__ sw, const float* __restrict__ bw,
              const float* __restrict__ compat,
              float* __restrict__ normb, float2* __restrict__ qnew,
              float2* __restrict__ out, int it) {
    __shared__ float g3s[32];
    const int t = threadIdx.x;
    const int i = blockIdx.x * 256 + t;
    if (t < DD) g3s[t] = exp2f(-(float)(t * t) * K3L);
    __syncthreads();

    const int z = i / SLICE;
    const int yx = i - z * SLICE;
    const int y = yx >> 4, x = yx & 15;

    // analytic spatial normalization
    float sx = 0.f, sy = 0.f, sz = 0.f;
#pragma unroll
    for (int xp = 0; xp < WW; ++xp) sx += g3s[iabs(x - xp)];
#pragma unroll
    for (int yp = 0; yp < HH; ++yp) sy += g3s[iabs(y - yp)];
#pragma unroll
    for (int zp = 0; zp < DD; ++zp) sz += g3s[iabs(z - zp)];
    const float inv_ns = 1.0f / (sx * sy * sz);

    const float I3 = rgb[i] * (1.f / 3.f);
    const float E = exp2f(-0.5f * LOG2E * I3 * I3);
    float Pt[NT];
    Pt[0] = E;
#pragma unroll
    for (int k = 1; k < NT; ++k) Pt[k] = Pt[k - 1] * I3;
    const float invf[NT] = {1.f, 1.f, 0.5f, 1.f / 6.f, 1.f / 24.f};

    float inv_nb;
    if (it == 0) {
        float nb = 0.f;
#pragma unroll
        for (int k = 0; k < NT; ++k)
            nb = fmaf(Pt[k] * invf[k], zout[(NFI + k) * NPTS + i], nb);
        normb[i] = nb;
        inv_nb = 1.0f / nb;
    } else {
        inv_nb = 1.0f / normb[i];
    }

    float b0 = 0.f, b1 = 0.f;
#pragma unroll
    for (int k = 0; k < NT; ++k) {
        float w = Pt[k] * invf[k];
        b0 = fmaf(w, zout[(2 + 2 * k) * NPTS + i], b0);
        b1 = fmaf(w, zout[(3 + 2 * k) * NPTS + i], b1);
    }
    b0 *= inv_nb;
    b1 *= inv_nb;

    float s0 = zout[i] * inv_ns;
    float s1 = zout[NPTS + i] * inv_ns;

    float m0 = s0 * sw[0] + b0 * bw[0];
    float m1 = s1 * sw[1] + b1 * bw[1];
    float p0 = fmaf(compat[0], m0, compat[1] * m1);
    float p1 = fmaf(compat[2], m0, compat[3] * m1);
    const float2 uu = u2[i];
    float2 qn = make_float2(uu.x - p0, uu.y - p1);
    qnew[i] = qn;
    if (it == 4) out[i] = qn;
}

extern "C" void kernel_launch(void* const* d_in, const int* in_sizes, int n_in,
                              void* d_out, int out_size, void* d_ws, size_t ws_size,
                              hipStream_t stream) {
    const float2* u2     = (const float2*)d_in[0];
    const float*  rgb    = (const float*)d_in[1];
    const float*  sw     = (const float*)d_in[2];
    const float*  bw     = (const float*)d_in[3];
    const float*  compat = (const float*)d_in[4];
    float2* out = (float2*)d_out;

    float* ws = (float*)d_ws;
    float*  tmp   = ws;                         // NFT*NPTS
    float*  zout  = ws + NFT * NPTS;            // NFT*NPTS
    float*  normb = ws + 2 * NFT * NPTS;        // NPTS
    float2* qnew  = (float2*)(ws + 2 * NFT * NPTS + NPTS);  // NPTS float2

    // precompute: xy-filter all 17 fields from q=u (planes 12..16 = P_t)
    k_xy<<<dim3(DD, NFT), SLICE, 0, stream>>>(u2, rgb, tmp);

    for (int it = 0; it < 5; ++it) {
        k_zconv<<<dim3(DD, it == 0 ? NFT : NFI), SLICE, 0, stream>>>(tmp, zout);
        k_update<<<NPTS / 256, 256, 0, stream>>>(zout, rgb, u2, sw, bw, compat,
                                                 normb, qnew, out, it);
        if (it < 4)
            k_xy<<<dim3(DD, NFI), SLICE, 0, stream>>>((const float2*)qnew, rgb, tmp);
    }
}